// Round 10
// baseline (576.314 us; speedup 1.0000x reference)
//
#include <hip/hip_runtime.h>

#define BB 8
#define SS 16
#define HH 512
#define WW 512
#define HWP (HH*WW)

// kC tiling
#define TH 16
#define TW 32
#define NH 612         // 18*34 halo elements
#define PLW 35         // padded LDS row stride (odd -> bank-friendly)
#define PLSZ 630       // 18*35 floats per plane

// workspace layout (float offsets)
#define WS_MSUM 0      // [8][16]
#define WS_FSUM 128    // [8][16][2]
#define WS_ACC  640    // num_s[16], l1x, l1y, l2x, l2y
#define WS_TOTAL 660

__device__ __forceinline__ float clip01(float x){ return fminf(fmaxf(x, 0.0f), 1.0f); }
__device__ __forceinline__ float pow045(float v){ return exp2f(0.45f * log2f(v)); }
__device__ __forceinline__ float cbn(float x){ return pow045(x*x + 1e-6f); }

// ---------------- kernel A: mask sums + mask-weighted flow sums ----------------
// Block = (eighth q, segment s, batch b): streams 128KB contiguous of ONE mask
// plane + the matching flow run. 3 linear streams/block (DRAM row friendly),
// unroll-8 float4 register staging -> 24 independent loads in flight.
__global__ __launch_bounds__(256)
void kA(const float* __restrict__ flow, const float* __restrict__ masks,
        float* __restrict__ ws)
{
    const int q = blockIdx.x;   // 8 eighths of a plane (32768 floats each)
    const int s = blockIdx.y;
    const int b = blockIdx.z;

    const float* M = masks + ((size_t)(b*SS + s)) * HWP + q * 32768;
    const float* U = flow + (size_t)b * 2 * HWP + q * 32768;
    const float* V = U + HWP;

    float a0 = 0.f, a1 = 0.f, a2 = 0.f;

    for (int j = 0; j < 4; ++j){
        float4 m[8], u[8], v[8];
#pragma unroll
        for (int i = 0; i < 8; ++i){
            const int p = (j*2048 + i*256 + threadIdx.x) * 4;
            m[i] = *reinterpret_cast<const float4*>(M + p);
            u[i] = *reinterpret_cast<const float4*>(U + p);
            v[i] = *reinterpret_cast<const float4*>(V + p);
        }
#pragma unroll
        for (int i = 0; i < 8; ++i){
            a0 += (m[i].x + m[i].y) + (m[i].z + m[i].w);
            a1 += m[i].x*u[i].x + m[i].y*u[i].y + m[i].z*u[i].z + m[i].w*u[i].w;
            a2 += m[i].x*v[i].x + m[i].y*v[i].y + m[i].z*v[i].z + m[i].w*v[i].w;
        }
    }

#pragma unroll
    for (int o = 32; o > 0; o >>= 1){
        a0 += __shfl_down(a0, o, 64);
        a1 += __shfl_down(a1, o, 64);
        a2 += __shfl_down(a2, o, 64);
    }
    if ((threadIdx.x & 63) == 0){
        atomicAdd(ws + WS_MSUM + b*SS + s, a0);
        atomicAdd(ws + WS_FSUM + (b*SS + s)*2 + 0, a1);
        atomicAdd(ws + WS_FSUM + (b*SS + s)*2 + 1, a2);
    }
}

// ---------------- kernel C: mega-stage fused pass ----------------
// Stage ALL 16 mask tiles + flow (19 planes, 48KB LDS, 3 blocks/CU) behind ONE
// barrier; occ accumulated in registers during staging. Compute phase is
// barrier-free (round-3 math). Image Sobel via predicated direct global loads.
__global__ __launch_bounds__(256)
void kC(const float* __restrict__ flow, const float* __restrict__ image,
        const float* __restrict__ masks, float* __restrict__ ws)
{
    const int b  = blockIdx.z;
    const int h0 = blockIdx.y * TH;
    const int w0 = blockIdx.x * TW;
    const int tid = threadIdx.x;

    __shared__ float sP[18*PLSZ];   // 0..15 masks, 16 u, 17 v
    __shared__ float sOcc[PLSZ];
    __shared__ float sMean[2*SS];
    __shared__ float sRed[4][20];

    // fold kB: per-batch mean flow
    if (tid < 2*SS){
        const int s = tid >> 1;
        const float ms = fmaxf(ws[WS_MSUM + b*SS + s], 1e-6f);
        sMean[tid] = ws[WS_FSUM + (b*SS + s)*2 + (tid&1)] / ms;
    }

    // halo slots: tid, tid+256 always valid; tid+512 for tid<100
    int lli[3], gci[3]; bool hv[3];
#pragma unroll
    for (int k = 0; k < 3; ++k){
        const int idx = tid + k*256;
        hv[k] = (k < 2) || (tid < NH - 512);
        const int r = idx / 34, c = idx % 34;
        const int gh = min(max(h0 - 1 + r, 0), HH-1);
        const int gw = min(max(w0 - 1 + c, 0), WW-1);
        gci[k] = gh*WW + gw;
        lli[k] = r*PLW + c;
    }

    const float* mb  = masks + (size_t)b * SS * HWP;
    const float* flo = flow  + (size_t)b * 2 * HWP;
    const float* img = image + (size_t)b * 3 * HWP;

    float occA[3] = {0.f, 0.f, 0.f};
#pragma unroll
    for (int p = 0; p < 18; ++p){
        const float* src = (p < 16) ? (mb + (size_t)p * HWP)
                                    : (flo + (size_t)(p-16) * HWP);
#pragma unroll
        for (int k = 0; k < 3; ++k){
            if (hv[k]){
                const float v = src[gci[k]];
                if (p < 16) occA[k] += v;
                sP[p*PLSZ + lli[k]] = v;
            }
        }
    }
#pragma unroll
    for (int k = 0; k < 3; ++k) if (hv[k]) sOcc[lli[k]] = occA[k];
    __syncthreads();   // the ONE staging barrier

    // pixel pair: (h0+pr, w0+pc2) and (h0+pr, w0+pc2+1)
    const int pr  = tid >> 4;
    const int pc2 = (tid & 15) << 1;
    const int R = pr + 1;

    const float* sU = &sP[16*PLSZ];
    const float* sV = &sP[17*PLSZ];
    const float fu0 = sU[R*PLW + pc2+1], fu1 = sU[R*PLW + pc2+2];
    const float fv0 = sV[R*PLW + pc2+1], fv1 = sV[R*PLW + pc2+2];

    float numv[SS];
    float perS0 = 0.f, perS1 = 0.f;

#pragma unroll
    for (int s = 0; s < SS; ++s){
        const float* bufc = &sP[s*PLSZ];
        float cmx[4], cmn[4], mC0 = 0.f, mC1 = 0.f;
#pragma unroll
        for (int j = 0; j < 4; ++j){
            const float a = bufc[(pr  )*PLW + pc2 + j];
            const float m = bufc[(pr+1)*PLW + pc2 + j];
            const float d = bufc[(pr+2)*PLW + pc2 + j];
            cmx[j] = fmaxf(fmaxf(a, m), d);
            cmn[j] = fminf(fminf(a, m), d);
            if (j == 1) mC0 = m;
            if (j == 2) mC1 = m;
        }
        const float rng0 = fmaxf(fmaxf(cmx[0],cmx[1]),cmx[2]) - fminf(fminf(cmn[0],cmn[1]),cmn[2]);
        const float rng1 = fmaxf(fmaxf(cmx[1],cmx[2]),cmx[3]) - fminf(fminf(cmn[1],cmn[2]),cmn[3]);
        perS0 += clip01(rng0);
        perS1 += clip01(rng1);

        const float mu = sMean[2*s], mv = sMean[2*s+1];
        const float d0u = fu0-mu, d0v = fv0-mv, d1u = fu1-mu, d1v = fv1-mv;
        numv[s] = pow045(d0u*d0u + d0v*d0v + 1e-6f)*mC0
                + pow045(d1u*d1u + d1v*d1v + 1e-6f)*mC1;
    }

    float ox[4], on[4];
#pragma unroll
    for (int j = 0; j < 4; ++j){
        const float a = sOcc[(pr  )*PLW + pc2 + j];
        const float m = sOcc[(pr+1)*PLW + pc2 + j];
        const float d = sOcc[(pr+2)*PLW + pc2 + j];
        ox[j] = fmaxf(fmaxf(a, m), d);
        on[j] = fminf(fminf(a, m), d);
    }
    const float org0 = fmaxf(fmaxf(ox[0],ox[1]),ox[2]) - fminf(fminf(on[0],on[1]),on[2]);
    const float org1 = fmaxf(fmaxf(ox[1],ox[2]),ox[3]) - fminf(fminf(on[1],on[2]),on[3]);
    const float bnd0 = clip01(clip01(org0) + perS0);
    const float bnd1 = clip01(clip01(org1) + perS1);

    // Sobel via predicated direct global loads (zero padding)
    const int gh  = h0 + pr;
    const int gw0 = w0 + pc2;
    const bool vT = (gh >= 1), vB = (gh <= HH-2);
    const bool vm = (gw0 >= 1), vp3 = (gw0 <= WW-3);
    const int oT = max(gh-1, 0)*WW, oM = gh*WW, oB2 = min(gh+1, HH-1)*WW;
    const int c0 = max(gw0-1, 0), c1 = gw0, c2 = gw0+1, c3 = min(gw0+2, WW-1);

    float mag0 = 0.f, mag1 = 0.f;
#pragma unroll
    for (int ch = 0; ch < 3; ++ch){
        const float* I = img + (size_t)ch * HWP;
        const float t0 = (vT&&vm) ? I[oT+c0] : 0.f;
        const float t1 =  vT      ? I[oT+c1] : 0.f;
        const float t2 =  vT      ? I[oT+c2] : 0.f;
        const float t3 = (vT&&vp3)? I[oT+c3] : 0.f;
        const float m0 =  vm      ? I[oM+c0] : 0.f;
        const float m1 =             I[oM+c1];
        const float m2 =             I[oM+c2];
        const float m3 =  vp3     ? I[oM+c3] : 0.f;
        const float b0 = (vB&&vm) ? I[oB2+c0] : 0.f;
        const float b1 =  vB      ? I[oB2+c1] : 0.f;
        const float b2 =  vB      ? I[oB2+c2] : 0.f;
        const float b3 = (vB&&vp3)? I[oB2+c3] : 0.f;

        const float gx0 = (t0 + 2.f*m0 + b0) - (t2 + 2.f*m2 + b2);
        const float gy0 = (t0 + 2.f*t1 + t2) - (b0 + 2.f*b1 + b2);
        const float gx1 = (t1 + 2.f*m1 + b1) - (t3 + 2.f*m3 + b3);
        const float gy1 = (t1 + 2.f*t2 + t3) - (b1 + 2.f*b2 + b3);
        mag0 += fabsf(gx0) + fabsf(gy0);
        mag1 += fabsf(gx1) + fabsf(gy1);
    }
    mag0 *= (1.f/3.f); mag1 *= (1.f/3.f);
    const float wgt0 = expf(-10.f * mag0) * (1.f - 0.9f*bnd0);
    const float wgt1 = expf(-10.f * mag1) * (1.f - 0.9f*bnd1);

    // flow smoothness (neighbors from LDS; exact border predicates)
    const int gw1 = gw0 + 1;
    const float lu = sU[R*PLW + pc2],     lv = sV[R*PLW + pc2];
    const float ru = sU[R*PLW + pc2 + 3], rv = sV[R*PLW + pc2 + 3];
    const float uu0 = sU[(R-1)*PLW + pc2+1], uv0 = sV[(R-1)*PLW + pc2+1];
    const float uu1 = sU[(R-1)*PLW + pc2+2], uv1 = sV[(R-1)*PLW + pc2+2];
    const float du0 = sU[(R+1)*PLW + pc2+1], dv0 = sV[(R+1)*PLW + pc2+1];
    const float du1 = sU[(R+1)*PLW + pc2+2], dv1 = sV[(R+1)*PLW + pc2+2];

    float l1x = 0.f, l1y = 0.f, l2x = 0.f, l2y = 0.f;

    if (gw0 >= 1) l1x += 0.5f * (cbn(fu0 - lu) + cbn(fv0 - lv)) * wgt0;
    l1x += 0.5f * (cbn(fu1 - fu0) + cbn(fv1 - fv0)) * wgt1;
    if (gh >= 1){
        l1y += 0.5f * (cbn(fu0 - uu0) + cbn(fv0 - uv0)) * wgt0;
        l1y += 0.5f * (cbn(fu1 - uu1) + cbn(fv1 - uv1)) * wgt1;
    }
    if (gw0 >= 1) l2x += cbn(fu1 - 2.f*fu0 + lu) + cbn(fv1 - 2.f*fv0 + lv);
    if (gw1 <= WW-2) l2x += cbn(ru - 2.f*fu1 + fu0) + cbn(rv - 2.f*fv1 + fv0);
    if (gh >= 1 && gh <= HH-2){
        l2y += cbn(du0 - 2.f*fu0 + uu0) + cbn(dv0 - 2.f*fv0 + uv0);
        l2y += cbn(du1 - 2.f*fu1 + uu1) + cbn(dv1 - 2.f*fv1 + uv1);
    }

    // block reduction of 20 values
    float vals[20];
#pragma unroll
    for (int s = 0; s < SS; ++s) vals[s] = numv[s];
    vals[16] = l1x; vals[17] = l1y; vals[18] = l2x; vals[19] = l2y;

    const int lane = tid & 63, wv = tid >> 6;
#pragma unroll
    for (int i = 0; i < 20; ++i){
        float v = vals[i];
#pragma unroll
        for (int o = 32; o > 0; o >>= 1) v += __shfl_down(v, o, 64);
        if (lane == 0) sRed[wv][i] = v;
    }
    __syncthreads();
    if (tid < 20){
        const float t = sRed[0][tid] + sRed[1][tid] + sRed[2][tid] + sRed[3][tid];
        atomicAdd(ws + WS_ACC + tid, t);
    }
}

// ---------------- finalize ----------------
__global__ void kF(const float* __restrict__ ws, float* __restrict__ out)
{
    __shared__ float sw[SS];
    const int t = threadIdx.x;
    if (t < SS){
        float w = 0.f;
        for (int b = 0; b < BB; ++b) w += fmaxf(ws[WS_MSUM + b*SS + t], 1e-6f);
        sw[t] = w;
    }
    __syncthreads();
    if (t == 0){
        float total = 0.f, tw = 0.f;
        for (int s = 0; s < SS; ++s){
            const float w = sw[s];
            total += (ws[WS_ACC + s] / fmaxf(w, 1e-6f)) * w;
            tw += w;
        }
        const float seg = (tw > 1e-6f) ? (total / tw) : 0.f;
        const float l1 = ws[WS_ACC+16] / (8.f*512.f*511.f) + ws[WS_ACC+17] / (8.f*511.f*512.f);
        const float l2 = ws[WS_ACC+18] / (8.f*2.f*512.f*510.f) + ws[WS_ACC+19] / (8.f*2.f*510.f*512.f);
        out[0] = 0.1f*seg + 0.15f*(l1 + 0.5f*l2);
    }
}

extern "C" void kernel_launch(void* const* d_in, const int* in_sizes, int n_in,
                              void* d_out, int out_size, void* d_ws, size_t ws_size,
                              hipStream_t stream)
{
    (void)in_sizes; (void)n_in; (void)out_size; (void)ws_size;
    const float* flow  = (const float*)d_in[0];
    const float* image = (const float*)d_in[1];
    const float* masks = (const float*)d_in[2];
    float* ws  = (float*)d_ws;
    float* out = (float*)d_out;

    (void)hipMemsetAsync(d_ws, 0, WS_TOTAL * sizeof(float), stream);

    dim3 gA(8, SS, BB);          // 1024 blocks, 3 contiguous streams each
    kA<<<gA, 256, 0, stream>>>(flow, masks, ws);
    dim3 gC(WW/TW, HH/TH, BB);   // (16, 32, 8)
    kC<<<gC, 256, 0, stream>>>(flow, image, masks, ws);
    kF<<<1, 64, 0, stream>>>(ws, out);
}

// Round 12
// 520.615 us; speedup vs baseline: 1.1070x; 1.1070x over previous
//
#include <hip/hip_runtime.h>

#define BB 8
#define SS 16
#define HH 512
#define WW 512
#define HWP (HH*WW)

// kC tiling
#define TH 16
#define TW 32
#define HR 18          // halo rows
#define HC 34          // halo cols
#define NH (HR*HC)     // 612 halo elements
#define LW 35          // padded LDS row stride

// workspace layout (float offsets)
#define WS_MSUM 0      // [8][16]
#define WS_FSUM 128    // [8][16][2]
#define WS_MEAN 384    // [8][16][2]
#define WS_ACC  640    // num_s[16], l1x, l1y, l2x, l2y
#define WS_TOTAL 660

__device__ __forceinline__ float clip01(float x){ return fminf(fmaxf(x, 0.0f), 1.0f); }
__device__ __forceinline__ float pow045(float v){ return exp2f(0.45f * log2f(v)); }
__device__ __forceinline__ float cbn(float x){ return pow045(x*x + 1e-6f); }

// ---------------- kernel A: mask sums + mask-weighted flow sums ----------------
// (round-10 version; measured < 149us, will surface in top-5 once kC drops)
__global__ __launch_bounds__(256)
void kA(const float* __restrict__ flow, const float* __restrict__ masks,
        float* __restrict__ ws)
{
    const int q = blockIdx.x;   // 8 eighths of a plane (32768 floats each)
    const int s = blockIdx.y;
    const int b = blockIdx.z;

    const float* M = masks + ((size_t)(b*SS + s)) * HWP + q * 32768;
    const float* U = flow + (size_t)b * 2 * HWP + q * 32768;
    const float* V = U + HWP;

    float a0 = 0.f, a1 = 0.f, a2 = 0.f;

    for (int j = 0; j < 4; ++j){
        float4 m[8], u[8], v[8];
#pragma unroll
        for (int i = 0; i < 8; ++i){
            const int p = (j*2048 + i*256 + threadIdx.x) * 4;
            m[i] = *reinterpret_cast<const float4*>(M + p);
            u[i] = *reinterpret_cast<const float4*>(U + p);
            v[i] = *reinterpret_cast<const float4*>(V + p);
        }
#pragma unroll
        for (int i = 0; i < 8; ++i){
            a0 += (m[i].x + m[i].y) + (m[i].z + m[i].w);
            a1 += m[i].x*u[i].x + m[i].y*u[i].y + m[i].z*u[i].z + m[i].w*u[i].w;
            a2 += m[i].x*v[i].x + m[i].y*v[i].y + m[i].z*v[i].z + m[i].w*v[i].w;
        }
    }

#pragma unroll
    for (int o = 32; o > 0; o >>= 1){
        a0 += __shfl_down(a0, o, 64);
        a1 += __shfl_down(a1, o, 64);
        a2 += __shfl_down(a2, o, 64);
    }
    if ((threadIdx.x & 63) == 0){
        atomicAdd(ws + WS_MSUM + b*SS + s, a0);
        atomicAdd(ws + WS_FSUM + (b*SS + s)*2 + 0, a1);
        atomicAdd(ws + WS_FSUM + (b*SS + s)*2 + 1, a2);
    }
}

// ---------------- kernel B: mean_flow = fsum / max(msum, 1e-6) ----------------
__global__ void kB(float* __restrict__ ws)
{
    const int i = threadIdx.x;            // 256 = 8*16*2
    const int bs = i >> 1;
    const float ms = fmaxf(ws[WS_MSUM + bs], 1e-6f);
    ws[WS_MEAN + i] = ws[WS_FSUM + i] / ms;
}

// ---------------- kernel C: round-3 structure; only change = occupancy constraint ----------------
// __launch_bounds__(256) + amdgpu_waves_per_eu(4): VGPR capped at 128 (compiler
// used 112 before), but no min-blocks metadata -> HW residency free to reach
// 4 blocks/CU (LDS 21KB allows 7).
__global__ __launch_bounds__(256) __attribute__((amdgpu_waves_per_eu(4)))
void kC(const float* __restrict__ flow, const float* __restrict__ image,
        const float* __restrict__ masks, float* __restrict__ ws)
{
    const int b  = blockIdx.z;
    const int h0 = blockIdx.y * TH;
    const int w0 = blockIdx.x * TW;
    const int tid = threadIdx.x;

    __shared__ float sImg[3][HR*LW];
    __shared__ float sFlo[2][HR*LW];
    __shared__ float sOcc[HR*LW];
    __shared__ float sMsk[2][HR*LW];
    __shared__ float sMean[2*SS];
    __shared__ float sRed[4][20];

    if (tid < 2*SS) sMean[tid] = ws[WS_MEAN + b*2*SS + tid];

    int hli[3], cgi[3]; bool hval[3]; bool hin[3]; int hgi[3];
#pragma unroll
    for (int k = 0; k < 3; ++k){
        const int idx = tid + k*256;
        hval[k] = (k < 2) || (tid < NH - 512);
        const int r = idx / HC, c = idx % HC;
        const int gh = h0 - 1 + r, gw = w0 - 1 + c;
        hli[k] = r*LW + c;
        hin[k] = ((unsigned)gh < (unsigned)HH) && ((unsigned)gw < (unsigned)WW);
        hgi[k] = gh*WW + gw;
        const int ch_ = min(max(gh, 0), HH-1);
        const int cw_ = min(max(gw, 0), WW-1);
        cgi[k] = ch_*WW + cw_;
    }

    const float* img = image + (size_t)b * 3 * HWP;
    const float* flo = flow  + (size_t)b * 2 * HWP;
    const float* mb  = masks + (size_t)b * SS * HWP;

#pragma unroll
    for (int k = 0; k < 3; ++k){
        if (hval[k]){
            const bool in = hin[k]; const int gi = hgi[k]; const int li = hli[k];
            sImg[0][li] = in ? img[0*HWP + gi] : 0.f;
            sImg[1][li] = in ? img[1*HWP + gi] : 0.f;
            sImg[2][li] = in ? img[2*HWP + gi] : 0.f;
            sFlo[0][li] = in ? flo[0*HWP + gi] : 0.f;
            sFlo[1][li] = in ? flo[1*HWP + gi] : 0.f;
        }
    }

    float occA[3] = {0.f, 0.f, 0.f};
    float pf[3];

#pragma unroll
    for (int k = 0; k < 3; ++k) if (hval[k]) pf[k] = mb[cgi[k]];
#pragma unroll
    for (int k = 0; k < 3; ++k) if (hval[k]){ sMsk[0][hli[k]] = pf[k]; occA[k] += pf[k]; }
#pragma unroll
    for (int k = 0; k < 3; ++k) if (hval[k]) pf[k] = mb[1*HWP + cgi[k]];
    __syncthreads();

    const int pr  = tid >> 4;
    const int pc2 = (tid & 15) << 1;
    const int R = pr + 1;
    const float fu0 = sFlo[0][R*LW + pc2+1], fu1 = sFlo[0][R*LW + pc2+2];
    const float fv0 = sFlo[1][R*LW + pc2+1], fv1 = sFlo[1][R*LW + pc2+2];

    float numv[SS];
    float perS0 = 0.f, perS1 = 0.f;

#pragma unroll
    for (int s = 0; s < SS; ++s){
        const float* bufc = sMsk[s & 1];
        float cmx[4], cmn[4], mC0 = 0.f, mC1 = 0.f;
#pragma unroll
        for (int j = 0; j < 4; ++j){
            const float a = bufc[(pr  )*LW + pc2 + j];
            const float m = bufc[(pr+1)*LW + pc2 + j];
            const float d = bufc[(pr+2)*LW + pc2 + j];
            cmx[j] = fmaxf(fmaxf(a, m), d);
            cmn[j] = fminf(fminf(a, m), d);
            if (j == 1) mC0 = m;
            if (j == 2) mC1 = m;
        }
        const float rng0 = fmaxf(fmaxf(cmx[0],cmx[1]),cmx[2]) - fminf(fminf(cmn[0],cmn[1]),cmn[2]);
        const float rng1 = fmaxf(fmaxf(cmx[1],cmx[2]),cmx[3]) - fminf(fminf(cmn[1],cmn[2]),cmn[3]);
        perS0 += clip01(rng0);
        perS1 += clip01(rng1);

        const float mu = sMean[2*s], mv = sMean[2*s+1];
        const float d0u = fu0-mu, d0v = fv0-mv, d1u = fu1-mu, d1v = fv1-mv;
        const float vm0 = pow045(d0u*d0u + d0v*d0v + 1e-6f);
        const float vm1 = pow045(d1u*d1u + d1v*d1v + 1e-6f);
        numv[s] = vm0*mC0 + vm1*mC1;

        if (s < SS-1){
#pragma unroll
            for (int k = 0; k < 3; ++k) if (hval[k]){ sMsk[(s+1)&1][hli[k]] = pf[k]; occA[k] += pf[k]; }
            if (s < SS-2){
#pragma unroll
                for (int k = 0; k < 3; ++k) if (hval[k]) pf[k] = mb[(s+2)*HWP + cgi[k]];
            }
            __syncthreads();
        }
    }

#pragma unroll
    for (int k = 0; k < 3; ++k) if (hval[k]) sOcc[hli[k]] = occA[k];
    __syncthreads();

    float ox[4], on[4];
#pragma unroll
    for (int j = 0; j < 4; ++j){
        const float a = sOcc[(pr  )*LW + pc2 + j];
        const float m = sOcc[(pr+1)*LW + pc2 + j];
        const float d = sOcc[(pr+2)*LW + pc2 + j];
        ox[j] = fmaxf(fmaxf(a, m), d);
        on[j] = fminf(fminf(a, m), d);
    }
    const float org0 = fmaxf(fmaxf(ox[0],ox[1]),ox[2]) - fminf(fminf(on[0],on[1]),on[2]);
    const float org1 = fmaxf(fmaxf(ox[1],ox[2]),ox[3]) - fminf(fminf(on[1],on[2]),on[3]);
    const float bnd0 = clip01(clip01(org0) + perS0);
    const float bnd1 = clip01(clip01(org1) + perS1);

    float mag0 = 0.f, mag1 = 0.f;
#pragma unroll
    for (int ch = 0; ch < 3; ++ch){
        float top[4], mid[4], bot[4];
#pragma unroll
        for (int j = 0; j < 4; ++j){
            top[j] = sImg[ch][(pr  )*LW + pc2 + j];
            mid[j] = sImg[ch][(pr+1)*LW + pc2 + j];
            bot[j] = sImg[ch][(pr+2)*LW + pc2 + j];
        }
        float colV0 = top[0] + 2.f*mid[0] + bot[0];
        float colV1 = top[1] + 2.f*mid[1] + bot[1];
        float colV2 = top[2] + 2.f*mid[2] + bot[2];
        float colV3 = top[3] + 2.f*mid[3] + bot[3];
        const float gx0 = colV0 - colV2;
        const float gx1 = colV1 - colV3;
        const float gy0 = (top[0] + 2.f*top[1] + top[2]) - (bot[0] + 2.f*bot[1] + bot[2]);
        const float gy1 = (top[1] + 2.f*top[2] + top[3]) - (bot[1] + 2.f*bot[2] + bot[3]);
        mag0 += fabsf(gx0) + fabsf(gy0);
        mag1 += fabsf(gx1) + fabsf(gy1);
    }
    mag0 *= (1.f/3.f); mag1 *= (1.f/3.f);
    const float wgt0 = expf(-10.f * mag0) * (1.f - 0.9f*bnd0);
    const float wgt1 = expf(-10.f * mag1) * (1.f - 0.9f*bnd1);

    const int gh  = h0 + pr;
    const int gw0 = w0 + pc2;
    const int gw1 = gw0 + 1;

    const float lu = sFlo[0][R*LW + pc2],     lv = sFlo[1][R*LW + pc2];
    const float ru = sFlo[0][R*LW + pc2 + 3], rv = sFlo[1][R*LW + pc2 + 3];
    const float uu0 = sFlo[0][(R-1)*LW + pc2+1], uv0 = sFlo[1][(R-1)*LW + pc2+1];
    const float uu1 = sFlo[0][(R-1)*LW + pc2+2], uv1 = sFlo[1][(R-1)*LW + pc2+2];
    const float du0 = sFlo[0][(R+1)*LW + pc2+1], dv0 = sFlo[1][(R+1)*LW + pc2+1];
    const float du1 = sFlo[0][(R+1)*LW + pc2+2], dv1 = sFlo[1][(R+1)*LW + pc2+2];

    float l1x = 0.f, l1y = 0.f, l2x = 0.f, l2y = 0.f;

    if (gw0 >= 1) l1x += 0.5f * (cbn(fu0 - lu) + cbn(fv0 - lv)) * wgt0;
    l1x += 0.5f * (cbn(fu1 - fu0) + cbn(fv1 - fv0)) * wgt1;
    if (gh >= 1){
        l1y += 0.5f * (cbn(fu0 - uu0) + cbn(fv0 - uv0)) * wgt0;
        l1y += 0.5f * (cbn(fu1 - uu1) + cbn(fv1 - uv1)) * wgt1;
    }
    if (gw0 >= 1) l2x += cbn(fu1 - 2.f*fu0 + lu) + cbn(fv1 - 2.f*fv0 + lv);
    if (gw1 <= WW-2) l2x += cbn(ru - 2.f*fu1 + fu0) + cbn(rv - 2.f*fv1 + fv0);
    if (gh >= 1 && gh <= HH-2){
        l2y += cbn(du0 - 2.f*fu0 + uu0) + cbn(dv0 - 2.f*fv0 + uv0);
        l2y += cbn(du1 - 2.f*fu1 + uu1) + cbn(dv1 - 2.f*fv1 + uv1);
    }

    float vals[20];
#pragma unroll
    for (int s = 0; s < SS; ++s) vals[s] = numv[s];
    vals[16] = l1x; vals[17] = l1y; vals[18] = l2x; vals[19] = l2y;

    const int lane = tid & 63, wv = tid >> 6;
#pragma unroll
    for (int i = 0; i < 20; ++i){
        float v = vals[i];
#pragma unroll
        for (int o = 32; o > 0; o >>= 1) v += __shfl_down(v, o, 64);
        if (lane == 0) sRed[wv][i] = v;
    }
    __syncthreads();
    if (tid < 20){
        const float t = sRed[0][tid] + sRed[1][tid] + sRed[2][tid] + sRed[3][tid];
        atomicAdd(ws + WS_ACC + tid, t);
    }
}

// ---------------- finalize ----------------
__global__ void kF(const float* __restrict__ ws, float* __restrict__ out)
{
    __shared__ float sw[SS];
    const int t = threadIdx.x;
    if (t < SS){
        float w = 0.f;
        for (int b = 0; b < BB; ++b) w += fmaxf(ws[WS_MSUM + b*SS + t], 1e-6f);
        sw[t] = w;
    }
    __syncthreads();
    if (t == 0){
        float total = 0.f, tw = 0.f;
        for (int s = 0; s < SS; ++s){
            const float w = sw[s];
            total += (ws[WS_ACC + s] / fmaxf(w, 1e-6f)) * w;
            tw += w;
        }
        const float seg = (tw > 1e-6f) ? (total / tw) : 0.f;
        const float l1 = ws[WS_ACC+16] / (8.f*512.f*511.f) + ws[WS_ACC+17] / (8.f*511.f*512.f);
        const float l2 = ws[WS_ACC+18] / (8.f*2.f*512.f*510.f) + ws[WS_ACC+19] / (8.f*2.f*510.f*512.f);
        out[0] = 0.1f*seg + 0.15f*(l1 + 0.5f*l2);
    }
}

extern "C" void kernel_launch(void* const* d_in, const int* in_sizes, int n_in,
                              void* d_out, int out_size, void* d_ws, size_t ws_size,
                              hipStream_t stream)
{
    (void)in_sizes; (void)n_in; (void)out_size; (void)ws_size;
    const float* flow  = (const float*)d_in[0];
    const float* image = (const float*)d_in[1];
    const float* masks = (const float*)d_in[2];
    float* ws  = (float*)d_ws;
    float* out = (float*)d_out;

    (void)hipMemsetAsync(d_ws, 0, WS_TOTAL * sizeof(float), stream);

    dim3 gA(8, SS, BB);          // 1024 blocks, 3 contiguous streams each
    kA<<<gA, 256, 0, stream>>>(flow, masks, ws);
    kB<<<1, 256, 0, stream>>>(ws);
    dim3 gC(WW/TW, HH/TH, BB);   // (16, 32, 8)
    kC<<<gC, 256, 0, stream>>>(flow, image, masks, ws);
    kF<<<1, 64, 0, stream>>>(ws, out);
}

// Round 13
// 381.444 us; speedup vs baseline: 1.5109x; 1.3649x over previous
//
#include <hip/hip_runtime.h>

#define BB 8
#define SS 16
#define HH 512
#define WW 512
#define HWP (HH*WW)

// kC tiling: 16x32 tile, 4 waves, each wave owns a 4-row strip
#define TH 16
#define TW 32
#define HR 18
#define HC 34
#define NH (HR*HC)     // 612 block halo elements
#define LW 35          // block plane stride
#define ST 35          // wave strip stride
#define SPL 210        // 6*35 floats per wave strip plane
#define NSH 204        // 6*34 strip halo elements

// workspace layout (float offsets)
#define WS_MSUM 0      // [8][16]
#define WS_FSUM 128    // [8][16][2]
#define WS_ACC  640    // num_s[16], l1x, l1y, l2x, l2y
#define WS_TOTAL 660

__device__ __forceinline__ float clip01(float x){ return fminf(fmaxf(x, 0.0f), 1.0f); }
__device__ __forceinline__ float pow045(float v){ return exp2f(0.45f * log2f(v)); }
__device__ __forceinline__ float cbn(float x){ return pow045(x*x + 1e-6f); }

// ---------------- kernel A: mask sums + mask-weighted flow sums ----------------
// (round-10 version, unchanged)
__global__ __launch_bounds__(256)
void kA(const float* __restrict__ flow, const float* __restrict__ masks,
        float* __restrict__ ws)
{
    const int q = blockIdx.x;
    const int s = blockIdx.y;
    const int b = blockIdx.z;

    const float* M = masks + ((size_t)(b*SS + s)) * HWP + q * 32768;
    const float* U = flow + (size_t)b * 2 * HWP + q * 32768;
    const float* V = U + HWP;

    float a0 = 0.f, a1 = 0.f, a2 = 0.f;

    for (int j = 0; j < 4; ++j){
        float4 m[8], u[8], v[8];
#pragma unroll
        for (int i = 0; i < 8; ++i){
            const int p = (j*2048 + i*256 + threadIdx.x) * 4;
            m[i] = *reinterpret_cast<const float4*>(M + p);
            u[i] = *reinterpret_cast<const float4*>(U + p);
            v[i] = *reinterpret_cast<const float4*>(V + p);
        }
#pragma unroll
        for (int i = 0; i < 8; ++i){
            a0 += (m[i].x + m[i].y) + (m[i].z + m[i].w);
            a1 += m[i].x*u[i].x + m[i].y*u[i].y + m[i].z*u[i].z + m[i].w*u[i].w;
            a2 += m[i].x*v[i].x + m[i].y*v[i].y + m[i].z*v[i].z + m[i].w*v[i].w;
        }
    }

#pragma unroll
    for (int o = 32; o > 0; o >>= 1){
        a0 += __shfl_down(a0, o, 64);
        a1 += __shfl_down(a1, o, 64);
        a2 += __shfl_down(a2, o, 64);
    }
    if ((threadIdx.x & 63) == 0){
        atomicAdd(ws + WS_MSUM + b*SS + s, a0);
        atomicAdd(ws + WS_FSUM + (b*SS + s)*2 + 0, a1);
        atomicAdd(ws + WS_FSUM + (b*SS + s)*2 + 1, a2);
    }
}

// ---------------- kernel C: wave-autonomous fused pass ----------------
// Block-wide: image+flow staged once (zero-padded), ONE barrier. Then each
// wave processes the 16-segment loop on its own 6x34 strip with wave-private
// double-buffered LDS + 2-deep register prefetch -> NO barriers in the loop
// (intra-wave LDS visibility is program-order via lgkmcnt). kB folded in.
__global__ __launch_bounds__(256, 2)
void kC(const float* __restrict__ flow, const float* __restrict__ image,
        const float* __restrict__ masks, float* __restrict__ ws)
{
    const int b  = blockIdx.z;
    const int h0 = blockIdx.y * TH;
    const int w0 = blockIdx.x * TW;
    const int tid = threadIdx.x;
    const int wv = tid >> 6, lane = tid & 63;

    __shared__ float sImg[3][HR*LW];
    __shared__ float sFlo[2][HR*LW];
    __shared__ float sMsk[4][2][SPL];
    __shared__ float sOccW[4][SPL];
    __shared__ float sMean[2*SS];
    __shared__ float sRed[4][20];

    // kB fold: per-batch mean flow
    if (tid < 2*SS){
        const int s = tid >> 1;
        const float ms = fmaxf(ws[WS_MSUM + b*SS + s], 1e-6f);
        sMean[tid] = ws[WS_FSUM + (b*SS + s)*2 + (tid&1)] / ms;
    }

    const float* img = image + (size_t)b * 3 * HWP;
    const float* flo = flow  + (size_t)b * 2 * HWP;
    const float* mb  = masks + (size_t)b * SS * HWP;

    // ---- block-wide image+flow staging (zero-padded OOB), round-3 pattern ----
#pragma unroll
    for (int k = 0; k < 3; ++k){
        const int idx = tid + k*256;
        const bool val = (k < 2) || (tid < NH - 512);
        if (val){
            const int r = idx / HC, c = idx % HC;
            const int gh = h0 - 1 + r, gw = w0 - 1 + c;
            const bool in = ((unsigned)gh < (unsigned)HH) && ((unsigned)gw < (unsigned)WW);
            const int gi = gh*WW + gw;
            const int li = r*LW + c;
            sImg[0][li] = in ? img[0*HWP + gi] : 0.f;
            sImg[1][li] = in ? img[1*HWP + gi] : 0.f;
            sImg[2][li] = in ? img[2*HWP + gi] : 0.f;
            sFlo[0][li] = in ? flo[0*HWP + gi] : 0.f;
            sFlo[1][li] = in ? flo[1*HWP + gi] : 0.f;
        }
    }

    // ---- wave strip slots (6 rows x 34 cols, clamped addressing for masks) ----
    int sgi[4], sli[4]; bool sval[4];
#pragma unroll
    for (int k = 0; k < 4; ++k){
        const int idx = k*64 + lane;
        sval[k] = (k < 3) || (lane < NSH - 192);
        const int r = idx / 34, c = idx % 34;
        const int gh = min(max(h0 + 4*wv - 1 + r, 0), HH-1);
        const int gw = min(max(w0 - 1 + c, 0), WW-1);
        sgi[k] = gh*WW + gw;
        sli[k] = r*ST + c;
    }

    float occA[4] = {0.f, 0.f, 0.f, 0.f};
    float t0[4], t1[4];

    // prologue: seg0 load+write, seg1 -> t0, seg2 -> t1
#pragma unroll
    for (int k = 0; k < 4; ++k) if (sval[k]) t0[k] = mb[sgi[k]];
#pragma unroll
    for (int k = 0; k < 4; ++k) if (sval[k]){ sMsk[wv][0][sli[k]] = t0[k]; occA[k] += t0[k]; }
#pragma unroll
    for (int k = 0; k < 4; ++k) if (sval[k]) t0[k] = mb[1*HWP + sgi[k]];
#pragma unroll
    for (int k = 0; k < 4; ++k) if (sval[k]) t1[k] = mb[2*HWP + sgi[k]];

    __syncthreads();   // sImg/sFlo/sMean ready (masks are wave-private)

    // ---- pixel pair (vertical): pixel0=(gh,gw), pixel1=(gh+1,gw) ----
    const int hi  = lane >> 5;
    const int col = lane & 31;
    const int gh  = h0 + 4*wv + 2*hi;
    const int gw  = w0 + col;
    const int lr  = 4*wv + 2*hi + 1;   // block-plane local row of pixel0
    const int lc  = col + 1;
    const int mr  = 2*hi;              // strip local top row of mask window
    const int mc  = col;               // strip local left col

    const float* sU = sFlo[0];
    const float* sV = sFlo[1];
    const float fu0 = sU[lr*LW + lc],     fu1 = sU[(lr+1)*LW + lc];
    const float fv0 = sV[lr*LW + lc],     fv1 = sV[(lr+1)*LW + lc];

    float numv[SS];
    float perS0 = 0.f, perS1 = 0.f;

#pragma unroll
    for (int s = 0; s < SS; ++s){
        const float* bufc = sMsk[wv][s & 1];
        float ax[3], bx[3], cx[3], dx[3];
#pragma unroll
        for (int j = 0; j < 3; ++j){
            ax[j] = bufc[(mr  )*ST + mc + j];
            bx[j] = bufc[(mr+1)*ST + mc + j];
            cx[j] = bufc[(mr+2)*ST + mc + j];
            dx[j] = bufc[(mr+3)*ST + mc + j];
        }
        float mx0 = -1e30f, mn0 = 1e30f, mx1 = -1e30f, mn1 = 1e30f;
#pragma unroll
        for (int j = 0; j < 3; ++j){
            const float u3 = fmaxf(fmaxf(ax[j], bx[j]), cx[j]);
            const float l3 = fminf(fminf(ax[j], bx[j]), cx[j]);
            const float u3b = fmaxf(fmaxf(bx[j], cx[j]), dx[j]);
            const float l3b = fminf(fminf(bx[j], cx[j]), dx[j]);
            mx0 = fmaxf(mx0, u3);  mn0 = fminf(mn0, l3);
            mx1 = fmaxf(mx1, u3b); mn1 = fminf(mn1, l3b);
        }
        perS0 += clip01(mx0 - mn0);
        perS1 += clip01(mx1 - mn1);

        const float mC0 = bx[1], mC1 = cx[1];
        const float mu = sMean[2*s], mv = sMean[2*s+1];
        const float d0u = fu0-mu, d0v = fv0-mv, d1u = fu1-mu, d1v = fv1-mv;
        numv[s] = pow045(d0u*d0u + d0v*d0v + 1e-6f)*mC0
                + pow045(d1u*d1u + d1v*d1v + 1e-6f)*mC1;

        if (s < SS-1){
#pragma unroll
            for (int k = 0; k < 4; ++k) if (sval[k]){ sMsk[wv][(s+1)&1][sli[k]] = t0[k]; occA[k] += t0[k]; }
#pragma unroll
            for (int k = 0; k < 4; ++k) t0[k] = t1[k];
            if (s < SS-3){
#pragma unroll
                for (int k = 0; k < 4; ++k) if (sval[k]) t1[k] = mb[(s+3)*HWP + sgi[k]];
            }
        }
    }

    // ---- occ range (wave-private plane; intra-wave visibility) ----
#pragma unroll
    for (int k = 0; k < 4; ++k) if (sval[k]) sOccW[wv][sli[k]] = occA[k];

    {
        // no barrier needed: same-wave write->read, program order
    }
    float oax[3], obx[3], ocx[3], odx[3];
#pragma unroll
    for (int j = 0; j < 3; ++j){
        oax[j] = sOccW[wv][(mr  )*ST + mc + j];
        obx[j] = sOccW[wv][(mr+1)*ST + mc + j];
        ocx[j] = sOccW[wv][(mr+2)*ST + mc + j];
        odx[j] = sOccW[wv][(mr+3)*ST + mc + j];
    }
    float omx0 = -1e30f, omn0 = 1e30f, omx1 = -1e30f, omn1 = 1e30f;
#pragma unroll
    for (int j = 0; j < 3; ++j){
        omx0 = fmaxf(omx0, fmaxf(fmaxf(oax[j], obx[j]), ocx[j]));
        omn0 = fminf(omn0, fminf(fminf(oax[j], obx[j]), ocx[j]));
        omx1 = fmaxf(omx1, fmaxf(fmaxf(obx[j], ocx[j]), odx[j]));
        omn1 = fminf(omn1, fminf(fminf(obx[j], ocx[j]), odx[j]));
    }
    const float bnd0 = clip01(clip01(omx0 - omn0) + perS0);
    const float bnd1 = clip01(clip01(omx1 - omn1) + perS1);

    // ---- Sobel from sImg (zero-padded borders already in LDS) ----
    float mag0 = 0.f, mag1 = 0.f;
#pragma unroll
    for (int ch = 0; ch < 3; ++ch){
        float iA[3], iB[3], iC[3], iD[3];
#pragma unroll
        for (int j = 0; j < 3; ++j){
            iA[j] = sImg[ch][(lr-1)*LW + lc-1 + j];
            iB[j] = sImg[ch][(lr  )*LW + lc-1 + j];
            iC[j] = sImg[ch][(lr+1)*LW + lc-1 + j];
            iD[j] = sImg[ch][(lr+2)*LW + lc-1 + j];
        }
        const float gx0 = (iA[0] + 2.f*iB[0] + iC[0]) - (iA[2] + 2.f*iB[2] + iC[2]);
        const float gy0 = (iA[0] + 2.f*iA[1] + iA[2]) - (iC[0] + 2.f*iC[1] + iC[2]);
        const float gx1 = (iB[0] + 2.f*iC[0] + iD[0]) - (iB[2] + 2.f*iC[2] + iD[2]);
        const float gy1 = (iB[0] + 2.f*iB[1] + iB[2]) - (iD[0] + 2.f*iD[1] + iD[2]);
        mag0 += fabsf(gx0) + fabsf(gy0);
        mag1 += fabsf(gx1) + fabsf(gy1);
    }
    mag0 *= (1.f/3.f); mag1 *= (1.f/3.f);
    const float wgt0 = expf(-10.f * mag0) * (1.f - 0.9f*bnd0);
    const float wgt1 = expf(-10.f * mag1) * (1.f - 0.9f*bnd1);

    // ---- flow smoothness (vertical-pair, r7-verified guards) ----
    const float uA  = sU[(lr-1)*LW + lc], vA_ = sV[(lr-1)*LW + lc];
    const float uD  = sU[(lr+2)*LW + lc], vD_ = sV[(lr+2)*LW + lc];
    const float uBm = sU[lr*LW + lc-1],     vBm = sV[lr*LW + lc-1];
    const float uBp = sU[lr*LW + lc+1],     vBp = sV[lr*LW + lc+1];
    const float uCm = sU[(lr+1)*LW + lc-1], vCm = sV[(lr+1)*LW + lc-1];
    const float uCp = sU[(lr+1)*LW + lc+1], vCp = sV[(lr+1)*LW + lc+1];

    float l1x = 0.f, l1y = 0.f, l2x = 0.f, l2y = 0.f;

    if (gw >= 1){
        l1x += 0.5f * (cbn(fu0 - uBm) + cbn(fv0 - vBm)) * wgt0;
        l1x += 0.5f * (cbn(fu1 - uCm) + cbn(fv1 - vCm)) * wgt1;
    }
    if (gh >= 1) l1y += 0.5f * (cbn(fu0 - uA) + cbn(fv0 - vA_)) * wgt0;
    l1y += 0.5f * (cbn(fu1 - fu0) + cbn(fv1 - fv0)) * wgt1;
    if (gw >= 1 && gw <= WW-2){
        l2x += cbn(uBp - 2.f*fu0 + uBm) + cbn(vBp - 2.f*fv0 + vBm);
        l2x += cbn(uCp - 2.f*fu1 + uCm) + cbn(vCp - 2.f*fv1 + vCm);
    }
    if (gh >= 1)      l2y += cbn(fu1 - 2.f*fu0 + uA) + cbn(fv1 - 2.f*fv0 + vA_);
    if (gh+1 <= HH-2) l2y += cbn(uD - 2.f*fu1 + fu0) + cbn(vD_ - 2.f*fv1 + fv0);

    // ---- block reduction of 20 values ----
    float vals[20];
#pragma unroll
    for (int s = 0; s < SS; ++s) vals[s] = numv[s];
    vals[16] = l1x; vals[17] = l1y; vals[18] = l2x; vals[19] = l2y;

#pragma unroll
    for (int i = 0; i < 20; ++i){
        float v = vals[i];
#pragma unroll
        for (int o = 32; o > 0; o >>= 1) v += __shfl_down(v, o, 64);
        if (lane == 0) sRed[wv][i] = v;
    }
    __syncthreads();
    if (tid < 20){
        const float t = sRed[0][tid] + sRed[1][tid] + sRed[2][tid] + sRed[3][tid];
        atomicAdd(ws + WS_ACC + tid, t);
    }
}

// ---------------- finalize ----------------
__global__ void kF(const float* __restrict__ ws, float* __restrict__ out)
{
    __shared__ float sw[SS];
    const int t = threadIdx.x;
    if (t < SS){
        float w = 0.f;
        for (int b = 0; b < BB; ++b) w += fmaxf(ws[WS_MSUM + b*SS + t], 1e-6f);
        sw[t] = w;
    }
    __syncthreads();
    if (t == 0){
        float total = 0.f, tw = 0.f;
        for (int s = 0; s < SS; ++s){
            const float w = sw[s];
            total += (ws[WS_ACC + s] / fmaxf(w, 1e-6f)) * w;
            tw += w;
        }
        const float seg = (tw > 1e-6f) ? (total / tw) : 0.f;
        const float l1 = ws[WS_ACC+16] / (8.f*512.f*511.f) + ws[WS_ACC+17] / (8.f*511.f*512.f);
        const float l2 = ws[WS_ACC+18] / (8.f*2.f*512.f*510.f) + ws[WS_ACC+19] / (8.f*2.f*510.f*512.f);
        out[0] = 0.1f*seg + 0.15f*(l1 + 0.5f*l2);
    }
}

extern "C" void kernel_launch(void* const* d_in, const int* in_sizes, int n_in,
                              void* d_out, int out_size, void* d_ws, size_t ws_size,
                              hipStream_t stream)
{
    (void)in_sizes; (void)n_in; (void)out_size; (void)ws_size;
    const float* flow  = (const float*)d_in[0];
    const float* image = (const float*)d_in[1];
    const float* masks = (const float*)d_in[2];
    float* ws  = (float*)d_ws;
    float* out = (float*)d_out;

    (void)hipMemsetAsync(d_ws, 0, WS_TOTAL * sizeof(float), stream);

    dim3 gA(8, SS, BB);
    kA<<<gA, 256, 0, stream>>>(flow, masks, ws);
    dim3 gC(WW/TW, HH/TH, BB);   // (16, 32, 8)
    kC<<<gC, 256, 0, stream>>>(flow, image, masks, ws);
    kF<<<1, 64, 0, stream>>>(ws, out);
}